// Round 5
// baseline (1011.670 us; speedup 1.0000x reference)
//
#include <hip/hip_runtime.h>
#include <math.h>

// Problem constants (from reference)
constexpr int NN = 50000;   // nodes
constexpr int NE = 800000;  // edges
constexpr int DD = 64;      // feature dim

// ---- wave reductions (64 lanes) ----
__device__ __forceinline__ float wave_max(float v) {
    #pragma unroll
    for (int off = 32; off > 0; off >>= 1) v = fmaxf(v, __shfl_xor(v, off, 64));
    return v;
}
__device__ __forceinline__ float wave_sum(float v) {
    #pragma unroll
    for (int off = 32; off > 0; off >>= 1) v += __shfl_xor(v, off, 64);
    return v;
}

// ---- column-per-lane 64x64 GEMM, zero allocas ----
// Lane j owns output column j. W column lives in 16 NAMED float4 SSA values
// (wc0..wc15) -> cannot be demoted to scratch (no alloca exists). x-row address
// is wave-uniform (readfirstlane'd index) -> scalar K$ loads. Inner op is
// v_fmac_f32(acc_v, x_s, w_v): 1 VALU instr per MAC.

#define LOADW(c) const float4 wc##c = make_float4( \
    W[(4*(c)+0)*DD + lane], W[(4*(c)+1)*DD + lane], \
    W[(4*(c)+2)*DD + lane], W[(4*(c)+3)*DD + lane]);

#define LOADW_ALL \
    LOADW(0) LOADW(1) LOADW(2)  LOADW(3)  LOADW(4)  LOADW(5)  LOADW(6)  LOADW(7) \
    LOADW(8) LOADW(9) LOADW(10) LOADW(11) LOADW(12) LOADW(13) LOADW(14) LOADW(15)

#define STEP(c, acc) { \
    const float4 xv = *(const float4*)(xrow + 4*(c)); \
    acc = fmaf(xv.x, wc##c.x, acc); \
    acc = fmaf(xv.y, wc##c.y, acc); \
    acc = fmaf(xv.z, wc##c.z, acc); \
    acc = fmaf(xv.w, wc##c.w, acc); }

#define STEP_ALL \
    STEP(0,a0)  STEP(1,a1)  STEP(2,a2)  STEP(3,a3) \
    STEP(4,a0)  STEP(5,a1)  STEP(6,a2)  STEP(7,a3) \
    STEP(8,a0)  STEP(9,a1)  STEP(10,a2) STEP(11,a3) \
    STEP(12,a0) STEP(13,a1) STEP(14,a2) STEP(15,a3)

// ---- kernel 1: zero degree histogram ----
__global__ void k_init(int* __restrict__ deg) {
    int i = blockIdx.x * blockDim.x + threadIdx.x;
    if (i < NN) deg[i] = 0;
}

// ---- kernel 2: receiver degree histogram ----
__global__ void k_count(const int* __restrict__ receivers, int* __restrict__ deg) {
    int e = blockIdx.x * blockDim.x + threadIdx.x;
    if (e < NE) atomicAdd(deg + receivers[e], 1);
}

// ---- kernel 3: exclusive scan of deg -> starts (single block, 1024 threads) ----
__global__ __launch_bounds__(1024) void k_scan(const int* __restrict__ deg,
                                               int* __restrict__ starts) {
    __shared__ int buf0[1024], buf1[1024];
    const int t = threadIdx.x;
    constexpr int C = (NN + 1023) / 1024;   // 49 nodes per thread
    int lo = t * C; if (lo > NN) lo = NN;
    int hi = lo + C; if (hi > NN) hi = NN;
    int s = 0;
    for (int i = lo; i < hi; ++i) s += deg[i];
    buf0[t] = s;
    __syncthreads();
    int* src = buf0; int* dst = buf1;
    for (int off = 1; off < 1024; off <<= 1) {
        int v = src[t] + ((t >= off) ? src[t - off] : 0);
        dst[t] = v;
        __syncthreads();
        int* tmp = src; src = dst; dst = tmp;
    }
    int run = (t == 0) ? 0 : src[t - 1];
    for (int i = lo; i < hi; ++i) { starts[i] = run; run += deg[i]; }
}

// ---- kernel 4: fill CSR edge index (starts advanced to segment ends) ----
__global__ void k_fill(const int* __restrict__ receivers,
                       int* __restrict__ starts, int* __restrict__ eidx) {
    int e = blockIdx.x * blockDim.x + threadIdx.x;
    if (e < NE) {
        int pos = atomicAdd(starts + receivers[e], 1);
        eidx[pos] = e;
    }
}

// ---- kernel 5: node projections (column-per-lane; wave m = wid&3 owns matrix m) ----
__global__ __launch_bounds__(256, 2) void k_node(
    const float* __restrict__ nodes,
    const float* __restrict__ Wsent, const float* __restrict__ bsent,
    const float* __restrict__ Wrecv, const float* __restrict__ brecv,
    const float* __restrict__ Wmsg,  const float* __restrict__ bmsg,
    const float* __restrict__ Wself, const float* __restrict__ bself,
    float* __restrict__ sentP, float* __restrict__ recvP,
    float* __restrict__ msgP,  float* __restrict__ selfOut) {
    const int lane = threadIdx.x & 63;
    const int wid  = (blockIdx.x * 256 + threadIdx.x) >> 6;
    const int nw   = (gridDim.x * 256) >> 6;
    const int m    = wid & 3;
    const int wsub = wid >> 2;
    const int nsub = nw >> 2;

    const float* W; const float* bias; float* out;
    if (m == 0)      { W = Wsent; bias = bsent; out = sentP; }
    else if (m == 1) { W = Wrecv; bias = brecv; out = recvP; }
    else if (m == 2) { W = Wmsg;  bias = bmsg;  out = msgP; }
    else             { W = Wself; bias = bself; out = selfOut; }

    LOADW_ALL                          // 64 floats in named float4 SSA values
    const float b = bias[lane];

    for (int i0 = wsub; i0 < NN; i0 += nsub) {
        const int i = __builtin_amdgcn_readfirstlane(i0);   // uniform
        const float* xrow = nodes + (size_t)i * DD;
        float a0 = b, a1 = 0.0f, a2 = 0.0f, a3 = 0.0f;
        STEP_ALL
        out[(size_t)i * DD + lane] = (a0 + a1) + (a2 + a3);
    }
}

// ---- kernel 6: edge features + attention logits (column-per-lane) ----
__global__ __launch_bounds__(256, 2) void k_edge(
    const float* __restrict__ edges,
    const int* __restrict__ senders, const int* __restrict__ receivers,
    const float* __restrict__ Wedge, const float* __restrict__ bedge,
    const float* __restrict__ Wattn, const float* __restrict__ battn,
    const float* __restrict__ sentP, const float* __restrict__ recvP,
    float* __restrict__ edgeOut, float* __restrict__ logits) {
    const int lane = threadIdx.x & 63;
    const int wid  = (blockIdx.x * 256 + threadIdx.x) >> 6;
    const int nw   = (gridDim.x * 256) >> 6;
    const float* W = Wedge;

    LOADW_ALL                          // 64 floats in named float4 SSA values
    const float be = bedge[lane];
    const float wa = Wattn[lane];
    const float ba = battn[0];

    for (int e0 = wid; e0 < NE; e0 += nw) {
        const int e = __builtin_amdgcn_readfirstlane(e0);   // uniform
        const int s = senders[e];        // scalar loads
        const int r = receivers[e];
        const float g0 = sentP[(size_t)s * DD + lane];      // coalesced gathers
        const float g1 = recvP[(size_t)r * DD + lane];
        const float* xrow = edges + (size_t)e * DD;         // uniform row
        float a0 = be, a1 = g0 + g1, a2 = 0.0f, a3 = 0.0f;
        STEP_ALL
        const float ef = (a0 + a1) + (a2 + a3);
        edgeOut[(size_t)e * DD + lane] = ef;                // coalesced store
        // attention logit: dot(ef, Wattn) + b, leaky_relu(0.01)
        float t = ef * wa;
        #pragma unroll
        for (int off = 32; off > 0; off >>= 1) t += __shfl_xor(t, off, 64);
        if (lane == 0) {
            float v = t + ba;
            v = v > 0.0f ? v : 0.01f * v;
            logits[e] = v;
        }
    }
}

// ---- kernel 7: per-node softmax + weighted message gather (no atomics) ----
__global__ void k_final(
    const int* __restrict__ ends, const int* __restrict__ eidx,
    const int* __restrict__ senders, const float* __restrict__ logits,
    const float* __restrict__ msgP, float* __restrict__ outNodes) {
    const int lane = threadIdx.x & 63;
    const int n = (blockIdx.x * 256 + threadIdx.x) >> 6;
    if (n >= NN) return;
    const int end = ends[n];
    const int beg = (n > 0) ? ends[n - 1] : 0;
    if (end == beg) return;            // empty segment: outNodes keeps selfOut

    float mloc = -1e30f;
    for (int b = beg + lane; b < end; b += 64)
        mloc = fmaxf(mloc, logits[eidx[b]]);
    const float m = wave_max(mloc);

    float sloc = 0.0f;
    for (int b = beg + lane; b < end; b += 64)
        sloc += expf(logits[eidx[b]] - m);
    const float inv = 1.0f / wave_sum(sloc);

    float acc0 = 0.0f, acc1 = 0.0f;
    int b = beg;
    for (; b + 2 <= end; b += 2) {
        const int e0 = eidx[b], e1 = eidx[b + 1];         // uniform loads
        const int s0 = senders[e0], s1 = senders[e1];
        const float w0 = expf(logits[e0] - m);
        const float w1 = expf(logits[e1] - m);
        acc0 += w0 * msgP[(size_t)s0 * DD + lane];        // coalesced rows
        acc1 += w1 * msgP[(size_t)s1 * DD + lane];
    }
    if (b < end) {
        const int e0 = eidx[b];
        acc0 += expf(logits[e0] - m) * msgP[(size_t)senders[e0] * DD + lane];
    }
    outNodes[(size_t)n * DD + lane] += (acc0 + acc1) * inv;   // on top of selfOut
}

extern "C" void kernel_launch(void* const* d_in, const int* in_sizes, int n_in,
                              void* d_out, int out_size, void* d_ws, size_t ws_size,
                              hipStream_t stream) {
    const float* nodes     = (const float*)d_in[0];
    const float* edges     = (const float*)d_in[1];
    const int*   senders   = (const int*)d_in[2];
    const int*   receivers = (const int*)d_in[3];
    const float* Wsent = (const float*)d_in[4];
    const float* bsent = (const float*)d_in[5];
    const float* Wrecv = (const float*)d_in[6];
    const float* brecv = (const float*)d_in[7];
    const float* Wedge = (const float*)d_in[8];
    const float* bedge = (const float*)d_in[9];
    const float* Wattn = (const float*)d_in[10];
    const float* battn = (const float*)d_in[11];
    const float* Wmsg  = (const float*)d_in[12];
    const float* bmsg  = (const float*)d_in[13];
    const float* Wself = (const float*)d_in[14];
    const float* bself = (const float*)d_in[15];

    float* out = (float*)d_out;
    float* outNodes = out;                    // [NN, DD]
    float* outEdge  = out + (size_t)NN * DD;  // [NE, DD]

    // workspace layout
    float* ws = (float*)d_ws;
    float* sentP  = ws;                       // NN*DD floats
    float* recvP  = sentP + (size_t)NN * DD;  // NN*DD
    float* msgP   = recvP + (size_t)NN * DD;  // NN*DD
    float* logits = msgP  + (size_t)NN * DD;  // NE
    int*   deg    = (int*)(logits + NE);      // NN ints
    int*   starts = deg + NN;                 // NN ints
    int*   eidx   = starts + NN;              // NE ints

    k_init <<<(NN + 255) / 256, 256, 0, stream>>>(deg);
    k_count<<<(NE + 255) / 256, 256, 0, stream>>>(receivers, deg);
    k_scan <<<1, 1024, 0, stream>>>(deg, starts);
    k_fill <<<(NE + 255) / 256, 256, 0, stream>>>(receivers, starts, eidx);
    k_node <<<1024, 256, 0, stream>>>(nodes, Wsent, bsent, Wrecv, brecv,
                                      Wmsg, bmsg, Wself, bself,
                                      sentP, recvP, msgP, outNodes);
    k_edge <<<4096, 256, 0, stream>>>(edges, senders, receivers, Wedge, bedge,
                                      Wattn, battn, sentP, recvP,
                                      outEdge, logits);
    k_final<<<(NN * 64 + 255) / 256, 256, 0, stream>>>(starts, eidx, senders,
                                                       logits, msgP, outNodes);
}